// Round 24
// baseline (383.988 us; speedup 1.0000x reference)
//
#include <hip/hip_runtime.h>

#define HDIM  64
#define INDIM 7
#define QDIM  3
#define TDEC  288
#define SEQ   512
#define NBT   8        // batches per block; 512-thread block; grid 256 = 1 block/CU
#define CHUNK 32       // x timesteps staged per LDS chunk
#define HPAD  68       // fp32 h/c row stride (decoder handoff)
#define GPAD  264      // lds_g row stride (decoder gbase only)
#define HBST  80       // bf16 h row stride in shorts (160B)
#define PXU   264      // px floats per batch row

typedef __attribute__((ext_vector_type(8))) short bf16x8;   // 8 bf16 in 4 VGPRs
typedef __attribute__((ext_vector_type(4))) float f32x4;

__device__ __forceinline__ float fast_rcp(float x) { return __builtin_amdgcn_rcpf(x); }
__device__ __forceinline__ float sigm(float x) { return fast_rcp(1.0f + __expf(-x)); }
// 5-op inf-safe tanh: 1 - 2/(1+e^{2x})
__device__ __forceinline__ float tanh_f(float x) {
    float e = __expf(2.0f * x);
    return fmaf(-2.0f, fast_rcp(1.0f + e), 1.0f);
}
// round-to-nearest-even fp32 -> bf16 bits
__device__ __forceinline__ short f2bf(float f) {
    union { float f; unsigned u; } v; v.f = f;
    unsigned r = (v.u + 0x7fffu + ((v.u >> 16) & 1u)) >> 16;
    return (short)r;
}
__device__ __forceinline__ float bf2f(short s) {
    union { unsigned u; float f; } v; v.u = ((unsigned)(unsigned short)s) << 16;
    return v.f;
}

// DPP-based add of a lane-permuted copy (VALU rate, no DS pipe).
template<int CTRL>
__device__ __forceinline__ float dpp_add(float v) {
    int p = __builtin_amdgcn_update_dpp(0, __float_as_int(v), CTRL, 0xF, 0xF, true);
    return v + __int_as_float(p);
}
// full 64-lane sum, all lanes receive the result.
__device__ __forceinline__ float wave_sum(float v) {
    v = dpp_add<0xB1>(v);    // quad_perm xor1
    v = dpp_add<0x4E>(v);    // quad_perm xor2
    v = dpp_add<0x124>(v);   // row_ror:4
    v = dpp_add<0x128>(v);   // row_ror:8 -> 16-lane row sum
    v += __shfl_xor(v, 16);
    v += __shfl_xor(v, 32);
    return v;
}

// R24 = R23 (single-bf16 W and h; 4 main MFMA/wave/step; px via MFMA; DPP
// decoder reduction) + two changes:
//  (1) xW DUTY-STAGGER: wave w runs its compute_xw share at s%4 == (wid&3)
//      instead of all waves bursting at s%4==0 -> per-step instruction mixes
//      differ across waves, breaking the lockstep pipe contention; total
//      work, write-before-read legality and dbuf disjointness unchanged.
//  (2) x stored as SINGLE RNE bf16 (x-lo dropped): xW 2-pass, half the x
//      staging. Predicted absmax ~1.1-1.5e-3 (threshold 3.24e-3).
__global__ __launch_bounds__(512, 2)
void enc_dec_kernel(const float* __restrict__ x,
                    const float* __restrict__ eWih, const float* __restrict__ eWhh,
                    const float* __restrict__ ebih, const float* __restrict__ ebhh,
                    const float* __restrict__ dWih, const float* __restrict__ dWhh,
                    const float* __restrict__ dbih, const float* __restrict__ dbhh,
                    const float* __restrict__ oW,   const float* __restrict__ obv,
                    float* __restrict__ out)
{
    __shared__ __align__(16) short lds_hh[2][NBT][HBST];     // h bf16 (RNE), parity dbuf
    __shared__ __align__(16) short lds_xb[2][CHUNK][NBT][8]; // x bf16 (k0..6, k7=1.0)
    __shared__ __align__(16) short lds_xzero[8];             // zero stub (g16>0 reads)
    __shared__ __align__(16) float lds_px[2][4][NBT][PXU];   // pre_x, 4-step dbuf
    __shared__ __align__(16) float lds_hf[NBT][HPAD];        // fp32 h_enc (final step)
    __shared__ __align__(16) float lds_cf[NBT][HPAD];        // fp32 c_enc (final step)
    __shared__ __align__(16) float lds_g[NBT][GPAD];         // decoder gbase staging

    const int tid  = threadIdx.x;
    const int lane = tid & 63;
    const int wid  = tid >> 6;           // 0..7
    const int b0   = blockIdx.x * NBT;

    const int m    = lane & 15;          // A-row within tile / D col
    const int g16  = lane >> 4;          // k-subblock / D row-quad
    const int b_act = lane & 7;          // batch (cols 8..15 replicate 0..7)
    const int tsel  = (lane >> 3) & 1;   // which of the wave's 2 tiles this lane acts for
    const int u_act = wid * 8 + tsel * 4 + g16;   // unit this lane acts for

    // ---- main A-fragments, row-permuted, SINGLE bf16 (RNE) ----
    bf16x8 a_h[2][2];
#pragma unroll
    for (int tt = 0; tt < 2; ++tt) {
        const int t = 2 * wid + tt;
        const int row = (m & 3) * 64 + 4 * t + (m >> 2);
#pragma unroll
        for (int kt = 0; kt < 2; ++kt) {
            const float* p = eWhh + (size_t)row * HDIM + kt * 32 + g16 * 8;
            f32x4 v0 = *(const f32x4*)p;
            f32x4 v1 = *(const f32x4*)(p + 4);
#pragma unroll
            for (int e = 0; e < 4; ++e) a_h[tt][kt][e]     = f2bf(v0[e]);
#pragma unroll
            for (int e = 0; e < 4; ++e) a_h[tt][kt][4 + e] = f2bf(v1[e]);
        }
    }

    // ---- xW A-fragments: hi/lo (W precision kept); K=8: e<7 Wih, e==7 bias ----
    bf16x8 axh[2], axl[2];
#pragma unroll
    for (int tt = 0; tt < 2; ++tt) {
        const int t = 2 * wid + tt;
        const int row = (m & 3) * 64 + 4 * t + (m >> 2);
        if (g16 == 0) {
#pragma unroll
            for (int e = 0; e < 8; ++e) {
                float v = (e < 7) ? eWih[row * INDIM + e] : (ebih[row] + ebhh[row]);
                short hi = f2bf(v);
                axh[tt][e] = hi;
                axl[tt][e] = f2bf(v - bf2f(hi));
            }
        } else {
#pragma unroll
            for (int e = 0; e < 8; ++e) { axh[tt][e] = 0; axl[tt][e] = 0; }
        }
    }

    // ---- init: step 0 reads h parity buffer 1; zero stub ----
    lds_hh[1][wid][lane] = 0;
    if (tid < 8) lds_xzero[tid] = 0;
    float c_reg = 0.0f;          // c for (b_act, u_act)

    // ---- x chunk loader (single RNE bf16; k==7 slot = 1.0) ----
    auto load_x_chunk = [&](int xbuf, int s0) {
        for (int i = tid; i < NBT * CHUNK * 8; i += 512) {
            int b = i >> 8;          // CHUNK*8 == 256 per batch
            int r = i & 255;
            int ss = r >> 3;
            int k = r & 7;
            float v = (k < 7) ? x[((size_t)(b0 + b) * SEQ + (s0 + ss)) * INDIM + k] : 1.0f;
            lds_xb[xbuf][ss][b][k] = f2bf(v);
        }
    };

    // ---- xW GEMM for 4-step chunk j2 -> lds_px[j2&1] (this wave's 2 tiles) ----
    auto compute_xw = [&](int j2) {
        const int sbase = 4 * j2;
        const int xbuf  = (sbase >> 5) & 1;
        const int sr0   = sbase & 31;
        const int col16 = lane & 15;
        const int pxb   = j2 & 1;
        bf16x8 bx[2];
#pragma unroll
        for (int n = 0; n < 2; ++n) {
            const int srow = sr0 + 2 * n + (col16 >> 3);
            const short* ph = (g16 == 0) ? &lds_xb[xbuf][srow][lane & 7][0] : &lds_xzero[0];
            bx[n] = *(const bf16x8*)ph;
        }
#pragma unroll
        for (int tt = 0; tt < 2; ++tt) {
#pragma unroll
            for (int n = 0; n < 2; ++n) {
                f32x4 p = {0, 0, 0, 0};
                p = __builtin_amdgcn_mfma_f32_16x16x32_bf16(axh[tt], bx[n], p, 0, 0, 0);
                p = __builtin_amdgcn_mfma_f32_16x16x32_bf16(axl[tt], bx[n], p, 0, 0, 0);
                const int sl = 2 * n + (col16 >> 3);
                const int u  = 4 * (2 * wid + tt) + (lane >> 4);
                *(f32x4*)&lds_px[pxb][sl][lane & 7][u * 4] = p;
            }
        }
    };

    // ---- prologue: stage x chunk 0; px chunks 0 AND 1 (stagger shifts chunk-1
    // writes up to step 3, so chunk 1 (steps 4..7) must also be pre-filled;
    // staggered writes for chunk j2 land in steps 4(j2-1)..4(j2-1)+3, all
    // barrier-separated from first read at step 4*j2) ----
    load_x_chunk(0, 0);
    __syncthreads();
    compute_xw(0);
    compute_xw(1);
    __syncthreads();

    // ================= encoder: 512 serial steps, ONE barrier each =================
    for (int s = 0; s < SEQ; ++s) {
        const int cs  = s & (CHUNK - 1);
        const int rb  = (s & 1) ^ 1;   // h read-parity
        const int wb  = s & 1;         // h write-parity

        // ---- px prefetch for THIS step: issue first, use last ----
        f32x4 px4 = *(const f32x4*)&lds_px[(s >> 2) & 1][s & 3][b_act][u_act * 4];

        // ---- B fragments: 2 b128 reads of single-bf16 h ----
        bf16x8 bh[2];
#pragma unroll
        for (int kt = 0; kt < 2; ++kt)
            bh[kt] = *(const bf16x8*)&lds_hh[rb][b_act][kt * 32 + g16 * 8];

        // ---- main MFMA: 2 tiles x 2 kt = 4, two chains of depth 2 ----
        f32x4 acc0 = {0, 0, 0, 0}, acc1 = {0, 0, 0, 0};
#pragma unroll
        for (int kt = 0; kt < 2; ++kt) {
            acc0 = __builtin_amdgcn_mfma_f32_16x16x32_bf16(a_h[0][kt], bh[kt], acc0, 0, 0, 0);
            acc1 = __builtin_amdgcn_mfma_f32_16x16x32_bf16(a_h[1][kt], bh[kt], acc1, 0, 0, 0);
        }

        // ---- gates are the regs of the selected tile (4 cndmasks) ----
        float pre[4];
#pragma unroll
        for (int g = 0; g < 4; ++g) pre[g] = tsel ? acc1[g] : acc0[g];

        // ---- activation: one chain per lane, (b_act, u_act) ----
        {
#pragma unroll
            for (int g = 0; g < 4; ++g) pre[g] += px4[g];
            float ig = sigm(pre[0]), fg = sigm(pre[1]), gg = tanh_f(pre[2]), og = sigm(pre[3]);
            c_reg = fg * c_reg + ig * gg;
            float h = og * tanh_f(c_reg);
            lds_hh[wb][b_act][u_act] = f2bf(h);   // single RNE bf16
            if (s + 1 == SEQ) {
                lds_hf[b_act][u_act] = h;
                lds_cf[b_act][u_act] = c_reg;
            }
        }

        // ---- xW duty-staggered: wave w contributes its tiles at s%4==(wid&3),
        // for the chunk TWO ahead of the one containing s (writes for chunk
        // (s>>2)+2 happen during steps 4*((s>>2)+1)-4 .. -1: >=1 barrier before
        // its first read; dbuf plane (j2&1) disjoint from current read plane) ----
        {
            const int j2 = (s >> 2) + 2;
            if ((s & 3) == (wid & 3) && 4 * j2 < SEQ) compute_xw(j2);
        }

        // ---- prefetch next x chunk ----
        if (cs == 0 && s + CHUNK < SEQ) {
            load_x_chunk(((s >> 5) & 1) ^ 1, s + CHUNK);
        }
        __syncthreads();   // h[wb] + px published for next step
    }
    // lds_hf/lds_cf hold h_enc/c_enc in (b, j) layout

    // ====== decoder gbase = b + h_enc @ dW_hh.T (fp32, one-time, 8 batches) ======
    {
        const int row = tid & 255;        // gate-matrix row
        const int gh  = tid >> 8;         // 0 -> batches 0-3, 1 -> batches 4-7
        float4 dwhh[16];
#pragma unroll
        for (int m4 = 0; m4 < 16; ++m4)
            dwhh[m4] = *reinterpret_cast<const float4*>(&dWhh[row * HDIM + m4 * 4]);
        const float dbias = dbih[row] + dbhh[row];

        float accd[4];
#pragma unroll
        for (int b = 0; b < 4; ++b) accd[b] = dbias;
#pragma unroll
        for (int m4 = 0; m4 < 16; ++m4) {
            const float4 w = dwhh[m4];
            float4 hv[4];
#pragma unroll
            for (int b = 0; b < 4; ++b)
                hv[b] = *reinterpret_cast<const float4*>(&lds_hf[gh * 4 + b][m4 * 4]);
#pragma unroll
            for (int b = 0; b < 4; ++b) accd[b] = fmaf(hv[b].x, w.x, accd[b]);
#pragma unroll
            for (int b = 0; b < 4; ++b) accd[b] = fmaf(hv[b].y, w.y, accd[b]);
#pragma unroll
            for (int b = 0; b < 4; ++b) accd[b] = fmaf(hv[b].z, w.z, accd[b]);
#pragma unroll
            for (int b = 0; b < 4; ++b) accd[b] = fmaf(hv[b].w, w.w, accd[b]);
        }
#pragma unroll
        for (int b = 0; b < 4; ++b) lds_g[gh * 4 + b][row] = accd[b];
    }
    __syncthreads();

    // ================= decoder: wave = one batch (8 waves, 8 batches) =================
    {
        const int b = wid, j = lane;
        const float c_e = lds_cf[b][j];
        const float gb0 = lds_g[b][j];
        const float gb1 = lds_g[b][HDIM + j];
        const float gb2 = lds_g[b][2 * HDIM + j];
        const float gb3 = lds_g[b][3 * HDIM + j];

        const float w00 = dWih[(0 * HDIM + j) * QDIM + 0], w01 = dWih[(0 * HDIM + j) * QDIM + 1], w02 = dWih[(0 * HDIM + j) * QDIM + 2];
        const float w10 = dWih[(1 * HDIM + j) * QDIM + 0], w11 = dWih[(1 * HDIM + j) * QDIM + 1], w12 = dWih[(1 * HDIM + j) * QDIM + 2];
        const float w20 = dWih[(2 * HDIM + j) * QDIM + 0], w21 = dWih[(2 * HDIM + j) * QDIM + 1], w22 = dWih[(2 * HDIM + j) * QDIM + 2];
        const float w30 = dWih[(3 * HDIM + j) * QDIM + 0], w31 = dWih[(3 * HDIM + j) * QDIM + 1], w32 = dWih[(3 * HDIM + j) * QDIM + 2];
        const float ow0 = oW[0 * HDIM + j], ow1 = oW[1 * HDIM + j], ow2 = oW[2 * HDIM + j];
        const float ob0 = obv[0], ob1 = obv[1], ob2 = obv[2];

        float y0 = 0.0f, y1 = 0.0f, y2 = 0.0f;
        float* outp = out + (size_t)(b0 + b) * TDEC * QDIM;

        for (int t = 0; t < TDEC; ++t) {
            float g0 = gb0 + y0 * w00 + y1 * w01 + y2 * w02;
            float g1 = gb1 + y0 * w10 + y1 * w11 + y2 * w12;
            float g2 = gb2 + y0 * w20 + y1 * w21 + y2 * w22;
            float g3 = gb3 + y0 * w30 + y1 * w31 + y2 * w32;
            float ig = sigm(g0), fg = sigm(g1), gg = tanh_f(g2), og = sigm(g3);
            float c = fg * c_e + ig * gg;
            float h = og * tanh_f(c);
            float r0 = wave_sum(h * ow0);
            float r1 = wave_sum(h * ow1);
            float r2 = wave_sum(h * ow2);
            y0 = r0 + ob0;
            y1 = r1 + ob1;
            y2 = r2 + ob2;
            if (j < QDIM) outp[t * QDIM + j] = (j == 0) ? y0 : (j == 1) ? y1 : y2;
        }
    }
}

extern "C" void kernel_launch(void* const* d_in, const int* in_sizes, int n_in,
                              void* d_out, int out_size, void* d_ws, size_t ws_size,
                              hipStream_t stream) {
    (void)in_sizes; (void)n_in; (void)d_ws; (void)ws_size; (void)out_size;
    const float* x    = (const float*)d_in[0];
    const float* eWih = (const float*)d_in[1];
    const float* eWhh = (const float*)d_in[2];
    const float* ebih = (const float*)d_in[3];
    const float* ebhh = (const float*)d_in[4];
    const float* dWih = (const float*)d_in[5];
    const float* dWhh = (const float*)d_in[6];
    const float* dbih = (const float*)d_in[7];
    const float* dbhh = (const float*)d_in[8];
    const float* oW   = (const float*)d_in[9];
    const float* obv  = (const float*)d_in[10];
    float* out = (float*)d_out;

    const int B = 2048;
    dim3 grid(B / NBT), block(512);
    enc_dec_kernel<<<grid, block, 0, stream>>>(x, eWih, eWhh, ebih, ebhh,
                                               dWih, dWhh, dbih, dbhh, oW, obv, out);
}

// Round 25
// 355.506 us; speedup vs baseline: 1.0801x; 1.0801x over previous
//
#include <hip/hip_runtime.h>

#define HDIM  64
#define INDIM 7
#define QDIM  3
#define TDEC  288
#define SEQ   512
#define NBT   8        // batches per block; 512-thread block; grid 256 = 1 block/CU
#define CHUNK 32       // x timesteps staged per LDS chunk
#define HPAD  68       // fp32 h/c row stride (decoder handoff)
#define GPAD  264      // lds_g row stride (decoder gbase only)
#define HBST  80       // bf16 h row stride in shorts (160B)
#define PXU   264      // px floats per batch row

typedef __attribute__((ext_vector_type(8))) short bf16x8;   // 8 bf16 in 4 VGPRs
typedef __attribute__((ext_vector_type(4))) float f32x4;

__device__ __forceinline__ float fast_rcp(float x) { return __builtin_amdgcn_rcpf(x); }
__device__ __forceinline__ float sigm(float x) { return fast_rcp(1.0f + __expf(-x)); }
// 5-op inf-safe tanh: 1 - 2/(1+e^{2x})
__device__ __forceinline__ float tanh_f(float x) {
    float e = __expf(2.0f * x);
    return fmaf(-2.0f, fast_rcp(1.0f + e), 1.0f);
}
// round-to-nearest-even fp32 -> bf16 bits
__device__ __forceinline__ short f2bf(float f) {
    union { float f; unsigned u; } v; v.f = f;
    unsigned r = (v.u + 0x7fffu + ((v.u >> 16) & 1u)) >> 16;
    return (short)r;
}
__device__ __forceinline__ float bf2f(short s) {
    union { unsigned u; float f; } v; v.u = ((unsigned)(unsigned short)s) << 16;
    return v.f;
}

// DPP-based add of a lane-permuted copy (VALU rate, no DS pipe).
// CTRL must be an immediate -> template parameter.
template<int CTRL>
__device__ __forceinline__ float dpp_add(float v) {
    int p = __builtin_amdgcn_update_dpp(0, __float_as_int(v), CTRL, 0xF, 0xF, true);
    return v + __int_as_float(p);
}
// full 64-lane sum, all lanes receive the result.
// Stages 1,2,4,8 on VALU (quad_perm xor1/xor2, row_ror 4/8 ring-sum);
// only xor16/xor32 on the DS pipe (shfl) -> DS chain depth 6 -> 2.
__device__ __forceinline__ float wave_sum(float v) {
    v = dpp_add<0xB1>(v);    // quad_perm(1,0,3,2)  = xor1
    v = dpp_add<0x4E>(v);    // quad_perm(2,3,0,1)  = xor2
    v = dpp_add<0x124>(v);   // row_ror:4
    v = dpp_add<0x128>(v);   // row_ror:8 -> 16-lane row sum in all lanes
    v += __shfl_xor(v, 16);
    v += __shfl_xor(v, 32);
    return v;
}

// R25 = R23 verbatim (best: 356.6 us, absmax 9.77e-4).
// Structure: 8 batches/block, 512 threads, grid 256 = 1 block/CU.
// Row-permuted A (gates land in acc regs); single-bf16 W and h (4 main
// MFMA/wave/step, chains of depth 2); x@Wih+bias precomputed via 3-pass
// hi/lo MFMA into lds_px in 4-step chunks (all waves, every 4th step —
// amortized + overlapped); px read hoisted to step top; one barrier/step;
// decoder reduction via DPP stages 1-8 + 2 shfl.
// R21 (2-block interleave), R24 (xW stagger, x-lo drop) both regressed: the
// per-step schedule is latency-bound at the HW-fixed 2 waves/SIMD point.
__global__ __launch_bounds__(512, 2)
void enc_dec_kernel(const float* __restrict__ x,
                    const float* __restrict__ eWih, const float* __restrict__ eWhh,
                    const float* __restrict__ ebih, const float* __restrict__ ebhh,
                    const float* __restrict__ dWih, const float* __restrict__ dWhh,
                    const float* __restrict__ dbih, const float* __restrict__ dbhh,
                    const float* __restrict__ oW,   const float* __restrict__ obv,
                    float* __restrict__ out)
{
    __shared__ __align__(16) short lds_hh[2][NBT][HBST];     // h bf16 (RNE), parity dbuf
    __shared__ __align__(16) short lds_xbh[2][CHUNK][NBT][8]; // x hi bf16 (k0..6, k7=1.0)
    __shared__ __align__(16) short lds_xbl[2][CHUNK][NBT][8]; // x lo bf16
    __shared__ __align__(16) short lds_xzero[8];             // zero stub (g16>0 reads)
    __shared__ __align__(16) float lds_px[2][4][NBT][PXU];   // pre_x, 4-step dbuf
    __shared__ __align__(16) float lds_hf[NBT][HPAD];        // fp32 h_enc (final step)
    __shared__ __align__(16) float lds_cf[NBT][HPAD];        // fp32 c_enc (final step)
    __shared__ __align__(16) float lds_g[NBT][GPAD];         // decoder gbase staging

    const int tid  = threadIdx.x;
    const int lane = tid & 63;
    const int wid  = tid >> 6;           // 0..7
    const int b0   = blockIdx.x * NBT;

    const int m    = lane & 15;          // A-row within tile / D col
    const int g16  = lane >> 4;          // k-subblock / D row-quad
    const int b_act = lane & 7;          // batch (cols 8..15 replicate 0..7)
    const int tsel  = (lane >> 3) & 1;   // which of the wave's 2 tiles this lane acts for
    const int u_act = wid * 8 + tsel * 4 + g16;   // unit this lane acts for

    // ---- main A-fragments, row-permuted, SINGLE bf16 (RNE) ----
    bf16x8 a_h[2][2];
#pragma unroll
    for (int tt = 0; tt < 2; ++tt) {
        const int t = 2 * wid + tt;
        const int row = (m & 3) * 64 + 4 * t + (m >> 2);
#pragma unroll
        for (int kt = 0; kt < 2; ++kt) {
            const float* p = eWhh + (size_t)row * HDIM + kt * 32 + g16 * 8;
            f32x4 v0 = *(const f32x4*)p;
            f32x4 v1 = *(const f32x4*)(p + 4);
#pragma unroll
            for (int e = 0; e < 4; ++e) a_h[tt][kt][e]     = f2bf(v0[e]);
#pragma unroll
            for (int e = 0; e < 4; ++e) a_h[tt][kt][4 + e] = f2bf(v1[e]);
        }
    }

    // ---- xW A-fragments: hi/lo (amortized precision); K=8: e<7 Wih, e==7 bias ----
    bf16x8 axh[2], axl[2];
#pragma unroll
    for (int tt = 0; tt < 2; ++tt) {
        const int t = 2 * wid + tt;
        const int row = (m & 3) * 64 + 4 * t + (m >> 2);
        if (g16 == 0) {
#pragma unroll
            for (int e = 0; e < 8; ++e) {
                float v = (e < 7) ? eWih[row * INDIM + e] : (ebih[row] + ebhh[row]);
                short hi = f2bf(v);
                axh[tt][e] = hi;
                axl[tt][e] = f2bf(v - bf2f(hi));
            }
        } else {
#pragma unroll
            for (int e = 0; e < 8; ++e) { axh[tt][e] = 0; axl[tt][e] = 0; }
        }
    }

    // ---- init: step 0 reads h parity buffer 1; zero stub ----
    lds_hh[1][wid][lane] = 0;
    if (tid < 8) lds_xzero[tid] = 0;
    float c_reg = 0.0f;          // c for (b_act, u_act)

    // ---- x chunk loader (bf16 hi/lo RNE split; k==7 slot = 1.0) ----
    auto load_x_chunk = [&](int xbuf, int s0) {
        for (int i = tid; i < NBT * CHUNK * 8; i += 512) {
            int b = i >> 8;          // CHUNK*8 == 256 per batch
            int r = i & 255;
            int ss = r >> 3;
            int k = r & 7;
            float v = (k < 7) ? x[((size_t)(b0 + b) * SEQ + (s0 + ss)) * INDIM + k] : 1.0f;
            short hi = f2bf(v);
            lds_xbh[xbuf][ss][b][k] = hi;
            lds_xbl[xbuf][ss][b][k] = f2bf(v - bf2f(hi));
        }
    };

    // ---- xW GEMM for 4-step chunk j2 -> lds_px[j2&1] (needs x staged) ----
    auto compute_xw = [&](int j2) {
        const int sbase = 4 * j2;
        const int xbuf  = (sbase >> 5) & 1;
        const int sr0   = sbase & 31;
        const int col16 = lane & 15;
        const int pxb   = j2 & 1;
        bf16x8 bxh[2], bxl[2];
#pragma unroll
        for (int n = 0; n < 2; ++n) {
            const int srow = sr0 + 2 * n + (col16 >> 3);
            const short* ph = (g16 == 0) ? &lds_xbh[xbuf][srow][lane & 7][0] : &lds_xzero[0];
            const short* pl = (g16 == 0) ? &lds_xbl[xbuf][srow][lane & 7][0] : &lds_xzero[0];
            bxh[n] = *(const bf16x8*)ph;
            bxl[n] = *(const bf16x8*)pl;
        }
#pragma unroll
        for (int tt = 0; tt < 2; ++tt) {
#pragma unroll
            for (int n = 0; n < 2; ++n) {
                f32x4 p = {0, 0, 0, 0};
                p = __builtin_amdgcn_mfma_f32_16x16x32_bf16(axh[tt], bxh[n], p, 0, 0, 0);
                p = __builtin_amdgcn_mfma_f32_16x16x32_bf16(axl[tt], bxh[n], p, 0, 0, 0);
                p = __builtin_amdgcn_mfma_f32_16x16x32_bf16(axh[tt], bxl[n], p, 0, 0, 0);
                const int sl = 2 * n + (col16 >> 3);
                const int u  = 4 * (2 * wid + tt) + (lane >> 4);
                *(f32x4*)&lds_px[pxb][sl][lane & 7][u * 4] = p;
            }
        }
    };

    // ---- prologue: stage x chunk 0, compute px chunk 0 ----
    load_x_chunk(0, 0);
    __syncthreads();
    compute_xw(0);
    __syncthreads();

    // ================= encoder: 512 serial steps, ONE barrier each =================
    for (int s = 0; s < SEQ; ++s) {
        const int cs  = s & (CHUNK - 1);
        const int rb  = (s & 1) ^ 1;   // h read-parity
        const int wb  = s & 1;         // h write-parity

        // ---- px prefetch for THIS step: issue first, use last ----
        f32x4 px4 = *(const f32x4*)&lds_px[(s >> 2) & 1][s & 3][b_act][u_act * 4];

        // ---- B fragments: 2 b128 reads of single-bf16 h ----
        bf16x8 bh[2];
#pragma unroll
        for (int kt = 0; kt < 2; ++kt)
            bh[kt] = *(const bf16x8*)&lds_hh[rb][b_act][kt * 32 + g16 * 8];

        // ---- main MFMA: 2 tiles x 2 kt = 4, two chains of depth 2 ----
        f32x4 acc0 = {0, 0, 0, 0}, acc1 = {0, 0, 0, 0};
#pragma unroll
        for (int kt = 0; kt < 2; ++kt) {
            acc0 = __builtin_amdgcn_mfma_f32_16x16x32_bf16(a_h[0][kt], bh[kt], acc0, 0, 0, 0);
            acc1 = __builtin_amdgcn_mfma_f32_16x16x32_bf16(a_h[1][kt], bh[kt], acc1, 0, 0, 0);
        }

        // ---- gates are the regs of the selected tile (4 cndmasks) ----
        float pre[4];
#pragma unroll
        for (int g = 0; g < 4; ++g) pre[g] = tsel ? acc1[g] : acc0[g];

        // ---- activation: one chain per lane, (b_act, u_act) ----
        {
#pragma unroll
            for (int g = 0; g < 4; ++g) pre[g] += px4[g];
            float ig = sigm(pre[0]), fg = sigm(pre[1]), gg = tanh_f(pre[2]), og = sigm(pre[3]);
            c_reg = fg * c_reg + ig * gg;
            float h = og * tanh_f(c_reg);
            lds_hh[wb][b_act][u_act] = f2bf(h);   // single RNE bf16
            if (s + 1 == SEQ) {
                lds_hf[b_act][u_act] = h;
                lds_cf[b_act][u_act] = c_reg;
            }
        }

        // ---- xW for the NEXT 4-chunk: off act's issue path ----
        if ((s & 3) == 0 && s + 4 < SEQ) compute_xw((s >> 2) + 1);

        // ---- prefetch next x chunk ----
        if (cs == 0 && s + CHUNK < SEQ) {
            load_x_chunk(((s >> 5) & 1) ^ 1, s + CHUNK);
        }
        __syncthreads();   // h[wb] + px published for next step
    }
    // lds_hf/lds_cf hold h_enc/c_enc in (b, j) layout

    // ====== decoder gbase = b + h_enc @ dW_hh.T (fp32, one-time, 8 batches) ======
    {
        const int row = tid & 255;        // gate-matrix row
        const int gh  = tid >> 8;         // 0 -> batches 0-3, 1 -> batches 4-7
        float4 dwhh[16];
#pragma unroll
        for (int m4 = 0; m4 < 16; ++m4)
            dwhh[m4] = *reinterpret_cast<const float4*>(&dWhh[row * HDIM + m4 * 4]);
        const float dbias = dbih[row] + dbhh[row];

        float accd[4];
#pragma unroll
        for (int b = 0; b < 4; ++b) accd[b] = dbias;
#pragma unroll
        for (int m4 = 0; m4 < 16; ++m4) {
            const float4 w = dwhh[m4];
            float4 hv[4];
#pragma unroll
            for (int b = 0; b < 4; ++b)
                hv[b] = *reinterpret_cast<const float4*>(&lds_hf[gh * 4 + b][m4 * 4]);
#pragma unroll
            for (int b = 0; b < 4; ++b) accd[b] = fmaf(hv[b].x, w.x, accd[b]);
#pragma unroll
            for (int b = 0; b < 4; ++b) accd[b] = fmaf(hv[b].y, w.y, accd[b]);
#pragma unroll
            for (int b = 0; b < 4; ++b) accd[b] = fmaf(hv[b].z, w.z, accd[b]);
#pragma unroll
            for (int b = 0; b < 4; ++b) accd[b] = fmaf(hv[b].w, w.w, accd[b]);
        }
#pragma unroll
        for (int b = 0; b < 4; ++b) lds_g[gh * 4 + b][row] = accd[b];
    }
    __syncthreads();

    // ================= decoder: wave = one batch (8 waves, 8 batches) =================
    {
        const int b = wid, j = lane;
        const float c_e = lds_cf[b][j];
        const float gb0 = lds_g[b][j];
        const float gb1 = lds_g[b][HDIM + j];
        const float gb2 = lds_g[b][2 * HDIM + j];
        const float gb3 = lds_g[b][3 * HDIM + j];

        const float w00 = dWih[(0 * HDIM + j) * QDIM + 0], w01 = dWih[(0 * HDIM + j) * QDIM + 1], w02 = dWih[(0 * HDIM + j) * QDIM + 2];
        const float w10 = dWih[(1 * HDIM + j) * QDIM + 0], w11 = dWih[(1 * HDIM + j) * QDIM + 1], w12 = dWih[(1 * HDIM + j) * QDIM + 2];
        const float w20 = dWih[(2 * HDIM + j) * QDIM + 0], w21 = dWih[(2 * HDIM + j) * QDIM + 1], w22 = dWih[(2 * HDIM + j) * QDIM + 2];
        const float w30 = dWih[(3 * HDIM + j) * QDIM + 0], w31 = dWih[(3 * HDIM + j) * QDIM + 1], w32 = dWih[(3 * HDIM + j) * QDIM + 2];
        const float ow0 = oW[0 * HDIM + j], ow1 = oW[1 * HDIM + j], ow2 = oW[2 * HDIM + j];
        const float ob0 = obv[0], ob1 = obv[1], ob2 = obv[2];

        float y0 = 0.0f, y1 = 0.0f, y2 = 0.0f;
        float* outp = out + (size_t)(b0 + b) * TDEC * QDIM;

        for (int t = 0; t < TDEC; ++t) {
            float g0 = gb0 + y0 * w00 + y1 * w01 + y2 * w02;
            float g1 = gb1 + y0 * w10 + y1 * w11 + y2 * w12;
            float g2 = gb2 + y0 * w20 + y1 * w21 + y2 * w22;
            float g3 = gb3 + y0 * w30 + y1 * w31 + y2 * w32;
            float ig = sigm(g0), fg = sigm(g1), gg = tanh_f(g2), og = sigm(g3);
            float c = fg * c_e + ig * gg;
            float h = og * tanh_f(c);
            // hybrid DPP + shfl reductions (3 independent chains interleave)
            float r0 = wave_sum(h * ow0);
            float r1 = wave_sum(h * ow1);
            float r2 = wave_sum(h * ow2);
            y0 = r0 + ob0;
            y1 = r1 + ob1;
            y2 = r2 + ob2;
            if (j < QDIM) outp[t * QDIM + j] = (j == 0) ? y0 : (j == 1) ? y1 : y2;
        }
    }
}

extern "C" void kernel_launch(void* const* d_in, const int* in_sizes, int n_in,
                              void* d_out, int out_size, void* d_ws, size_t ws_size,
                              hipStream_t stream) {
    (void)in_sizes; (void)n_in; (void)d_ws; (void)ws_size; (void)out_size;
    const float* x    = (const float*)d_in[0];
    const float* eWih = (const float*)d_in[1];
    const float* eWhh = (const float*)d_in[2];
    const float* ebih = (const float*)d_in[3];
    const float* ebhh = (const float*)d_in[4];
    const float* dWih = (const float*)d_in[5];
    const float* dWhh = (const float*)d_in[6];
    const float* dbih = (const float*)d_in[7];
    const float* dbhh = (const float*)d_in[8];
    const float* oW   = (const float*)d_in[9];
    const float* obv  = (const float*)d_in[10];
    float* out = (float*)d_out;

    const int B = 2048;
    dim3 grid(B / NBT), block(512);
    enc_dec_kernel<<<grid, block, 0, stream>>>(x, eWih, eWhh, ebih, ebhh,
                                               dWih, dWhh, dbih, dbhh, oW, obv, out);
}